// Round 7
// baseline (4441.538 us; speedup 1.0000x reference)
//
#include <hip/hip_runtime.h>

#define B_ 64
#define T_ 2048
#define F_ 8
#define H_ 128
#define G_ 512   // 4*H

typedef _Float16 v2h __attribute__((ext_vector_type(2)));

// pack two fp32 into one dword of two f16 (RTN)
__device__ __forceinline__ unsigned pk2h(float lo, float hi) {
    v2h p;
    p[0] = (_Float16)lo;
    p[1] = (_Float16)hi;
    return __builtin_bit_cast(unsigned, p);
}

#if __has_builtin(__builtin_amdgcn_fdot2)
__device__ __forceinline__ float fdot2a(unsigned a, unsigned b, float c) {
    return __builtin_amdgcn_fdot2(__builtin_bit_cast(v2h, a),
                                  __builtin_bit_cast(v2h, b), c, false);
}
#else
__device__ __forceinline__ float fdot2a(unsigned a, unsigned b, float c) {
    v2h av = __builtin_bit_cast(v2h, a);
    v2h bv = __builtin_bit_cast(v2h, b);
    c += (float)av[0] * (float)bv[0];
    c += (float)av[1] * (float)bv[1];
    return c;
}
#endif

__device__ __forceinline__ float tanh_f(float x) {
    float e = __expf(2.0f * x);
    return 1.0f - 2.0f / (e + 1.0f);
}

// 8-lane compacting butterfly: input 4 gate-partials (each a K-partial),
// output: lane base+0 -> gate0(i), +1 -> gate2(g), +2 -> gate1(f), +3 -> gate3(o)
// full sums (lanes +4..+7 mirror +0..+3).
__device__ __forceinline__ float red8(float v0, float v1, float v2, float v3, int l) {
    float s0 = v0 + __shfl_xor(v0, 1);
    float s1 = v1 + __shfl_xor(v1, 1);
    float s2 = v2 + __shfl_xor(v2, 1);
    float s3 = v3 + __shfl_xor(v3, 1);
    float u0 = (l & 1) ? s2 : s0;
    float u1 = (l & 1) ? s3 : s1;
    float z0 = u0 + __shfl_xor(u0, 2);
    float z1 = u1 + __shfl_xor(u1, 2);
    float w  = (l & 2) ? z1 : z0;
    w += __shfl_xor(w, 4);
    return w;
}

// LDS kept > 80 KB: enforces 1 WG/CU physically (we only launch 64 WGs on 256
// CUs anyway). VGPR-budget history: block-shape heuristic gave 64 @1024thr,
// 128 @512thr regardless of launch_bounds/waves_per_eu args (R2-R6).
// amdgpu_num_vgpr(256) overrides the heuristic cap directly: 8 waves/CU x 256
// regs = half the CU file, legal at 1 WG/CU. Live set ~225 -> spill-free.
#define XNF (T_ * F_ + 4096)

__global__ void __launch_bounds__(512, 1)
__attribute__((amdgpu_num_vgpr(256)))
lstm2_fused_kernel(const float* __restrict__ x,
                   const float* __restrict__ wih0,
                   const float* __restrict__ whh0,
                   const float* __restrict__ bih0,
                   const float* __restrict__ bhh0,
                   const float* __restrict__ wih1,
                   const float* __restrict__ whh1,
                   const float* __restrict__ bih1,
                   const float* __restrict__ bhh1,
                   const float* __restrict__ wlin,
                   const float* __restrict__ blin,
                   float* __restrict__ out)
{
    __shared__ __align__(16) float x_f[XNF];           // fp32 x, 80+ KB (oversized)
    __shared__ __align__(16) unsigned h0b[2][H_ / 2];  // h0 double-buffered, f16 pairs
    __shared__ __align__(16) unsigned h1b[2][H_ / 2];  // h1 double-buffered
    __shared__ __align__(16) unsigned wlin_p[G_];
    __shared__ float blin_f[F_];

    const int tid = threadIdx.x;    // 0..511
    const int l   = tid & 7;        // K-slice lane within group
    const int grp = tid >> 3;       // 0..63
    const int j0  = grp;            // first h index
    const int j1  = grp + 64;       // second h index
    const int b   = blockIdx.x;
    // gate owned by this lane after red8 compaction: 0->i,1->g,2->f,3->o
    const int l3   = l & 3;
    const int gate = ((l3 & 1) << 1) | (l3 >> 1);   // 0,2,1,3

    // ---- stage x[b] into LDS (fp32, exact) ----
    const float4* xp = (const float4*)(x + (size_t)b * T_ * F_);
    #pragma unroll
    for (int i = 0; i < 8; ++i) {
        int idx = tid + i * 512;
        float4 v = xp[idx];
        *(float4*)&x_f[idx * 4] = v;
    }

    // ---- weights: rows {q*128+j0, q*128+j1}, K-slice [16l,16l+16), 3 matrices ----
    unsigned rwhh0[64], rwih1[64], rwhh1[64];   // [jj*32 + q*8 + d]
    float    w0f[8];                            // wih0[q*128+j][l], [jj*4+q]
    #pragma unroll
    for (int jj = 0; jj < 2; ++jj) {
        int j = jj ? j1 : j0;
        #pragma unroll
        for (int q = 0; q < 4; ++q) {
            const float4* p0 = (const float4*)(whh0 + (size_t)(q * H_ + j) * H_ + l * 16);
            const float4* p1 = (const float4*)(wih1 + (size_t)(q * H_ + j) * H_ + l * 16);
            const float4* p2 = (const float4*)(whh1 + (size_t)(q * H_ + j) * H_ + l * 16);
            #pragma unroll
            for (int i = 0; i < 4; ++i) {
                float4 v0 = p0[i], v1 = p1[i], v2 = p2[i];
                int base = jj * 32 + q * 8 + i * 2;
                rwhh0[base + 0] = pk2h(v0.x, v0.y);
                rwhh0[base + 1] = pk2h(v0.z, v0.w);
                rwih1[base + 0] = pk2h(v1.x, v1.y);
                rwih1[base + 1] = pk2h(v1.z, v1.w);
                rwhh1[base + 0] = pk2h(v2.x, v2.y);
                rwhh1[base + 1] = pk2h(v2.z, v2.w);
            }
            w0f[jj * 4 + q] = wih0[(size_t)(q * H_ + j) * F_ + l];
        }
    }
    // per-lane biases for the gate this lane ends up owning (per j)
    const float bias0_0 = bih0[gate * H_ + j0] + bhh0[gate * H_ + j0];
    const float bias0_1 = bih0[gate * H_ + j1] + bhh0[gate * H_ + j1];
    const float bias1_0 = bih1[gate * H_ + j0] + bhh1[gate * H_ + j0];
    const float bias1_1 = bih1[gate * H_ + j1] + bhh1[gate * H_ + j1];
    const float A2 = (gate == 2) ? 2.0f : 1.0f;   // tanh for g-gate, sigmoid else

    wlin_p[tid] = pk2h(wlin[tid * 2], wlin[tid * 2 + 1]);
    if (tid < F_) blin_f[tid] = blin[tid];
    if (tid < H_) { ((unsigned*)h0b)[tid] = 0u; ((unsigned*)h1b)[tid] = 0u; }
    __syncthreads();

    const int bl = (tid & 63) & ~7;   // wave-lane base of this 8-group
    float c00 = 0.0f, c01 = 0.0f;     // layer-0 cells for j0, j1 (replicated in group)
    float c10 = 0.0f, c11 = 0.0f;     // layer-1 cells
    int p = 0;

    for (int t = 0; t < T_; ++t) {
        // ================= layer 0 =================
        float acc[8];
        {   // x contribution: lane l handles feature l (fp32 exact)
            float xv = x_f[t * F_ + l];
            #pragma unroll
            for (int r = 0; r < 8; ++r) acc[r] = w0f[r] * xv;
        }
        {
            uint4 hA = *(const uint4*)&h0b[p][l * 8];
            uint4 hB = *(const uint4*)&h0b[p][l * 8 + 4];
            #pragma unroll
            for (int r = 0; r < 8; ++r) {
                int base = r * 8;   // r = jj*4 + q
                float a = acc[r];
                a = fdot2a(rwhh0[base + 0], hA.x, a);
                a = fdot2a(rwhh0[base + 1], hA.y, a);
                a = fdot2a(rwhh0[base + 2], hA.z, a);
                a = fdot2a(rwhh0[base + 3], hA.w, a);
                a = fdot2a(rwhh0[base + 4], hB.x, a);
                a = fdot2a(rwhh0[base + 5], hB.y, a);
                a = fdot2a(rwhh0[base + 6], hB.z, a);
                a = fdot2a(rwhh0[base + 7], hB.w, a);
                acc[r] = a;
            }
        }
        float w0 = red8(acc[0], acc[1], acc[2], acc[3], l) + bias0_0;
        float w1 = red8(acc[4], acc[5], acc[6], acc[7], l) + bias0_1;
        float act0 = 1.0f - A2 / (__expf(A2 * w0) + 1.0f);
        float act1 = 1.0f - A2 / (__expf(A2 * w1) + 1.0f);
        {
            float gi0 = __shfl(act0, bl + 0), gg0 = __shfl(act0, bl + 1);
            float gf0 = __shfl(act0, bl + 2), go0 = __shfl(act0, bl + 3);
            float gi1 = __shfl(act1, bl + 0), gg1 = __shfl(act1, bl + 1);
            float gf1 = __shfl(act1, bl + 2), go1 = __shfl(act1, bl + 3);
            c00 = gf0 * c00 + gi0 * gg0;
            c01 = gf1 * c01 + gi1 * gg1;
            float hh0 = go0 * tanh_f(c00);
            float hh1 = go1 * tanh_f(c01);
            if (l == 0) {
                _Float16* hp = (_Float16*)h0b[1 - p];
                hp[j0] = (_Float16)hh0;
                hp[j1] = (_Float16)hh1;
            }
        }
        __syncthreads();

        // ================= layer 1 =================
        {
            uint4 hA = *(const uint4*)&h0b[1 - p][l * 8];
            uint4 hB = *(const uint4*)&h0b[1 - p][l * 8 + 4];
            #pragma unroll
            for (int r = 0; r < 8; ++r) {
                int base = r * 8;
                float a = 0.0f;
                a = fdot2a(rwih1[base + 0], hA.x, a);
                a = fdot2a(rwih1[base + 1], hA.y, a);
                a = fdot2a(rwih1[base + 2], hA.z, a);
                a = fdot2a(rwih1[base + 3], hA.w, a);
                a = fdot2a(rwih1[base + 4], hB.x, a);
                a = fdot2a(rwih1[base + 5], hB.y, a);
                a = fdot2a(rwih1[base + 6], hB.z, a);
                a = fdot2a(rwih1[base + 7], hB.w, a);
                acc[r] = a;
            }
            // reuse hA/hB for the recurrent operand to cap live registers
            hA = *(const uint4*)&h1b[p][l * 8];
            hB = *(const uint4*)&h1b[p][l * 8 + 4];
            #pragma unroll
            for (int r = 0; r < 8; ++r) {
                int base = r * 8;
                float a = acc[r];
                a = fdot2a(rwhh1[base + 0], hA.x, a);
                a = fdot2a(rwhh1[base + 1], hA.y, a);
                a = fdot2a(rwhh1[base + 2], hA.z, a);
                a = fdot2a(rwhh1[base + 3], hA.w, a);
                a = fdot2a(rwhh1[base + 4], hB.x, a);
                a = fdot2a(rwhh1[base + 5], hB.y, a);
                a = fdot2a(rwhh1[base + 6], hB.z, a);
                a = fdot2a(rwhh1[base + 7], hB.w, a);
                acc[r] = a;
            }
        }
        w0 = red8(acc[0], acc[1], acc[2], acc[3], l) + bias1_0;
        w1 = red8(acc[4], acc[5], acc[6], acc[7], l) + bias1_1;
        act0 = 1.0f - A2 / (__expf(A2 * w0) + 1.0f);
        act1 = 1.0f - A2 / (__expf(A2 * w1) + 1.0f);
        {
            float gi0 = __shfl(act0, bl + 0), gg0 = __shfl(act0, bl + 1);
            float gf0 = __shfl(act0, bl + 2), go0 = __shfl(act0, bl + 3);
            float gi1 = __shfl(act1, bl + 0), gg1 = __shfl(act1, bl + 1);
            float gf1 = __shfl(act1, bl + 2), go1 = __shfl(act1, bl + 3);
            c10 = gf0 * c10 + gi0 * gg0;
            c11 = gf1 * c11 + gi1 * gg1;
            float hh0 = go0 * tanh_f(c10);
            float hh1 = go1 * tanh_f(c11);
            if (l == 0) {
                _Float16* hp = (_Float16*)h1b[1 - p];
                hp[j0] = (_Float16)hh0;
                hp[j1] = (_Float16)hh1;
            }
        }
        __syncthreads();

        // ---------- output linear: wave 0, overlaps next step ----------
        if (tid < 64) {
            int fo = tid >> 3;
            int ll = tid & 7;
            float a = 0.0f;
            #pragma unroll
            for (int jj = 0; jj < 8; ++jj) {
                a = fdot2a(wlin_p[fo * 64 + ll * 8 + jj], h1b[1 - p][ll * 8 + jj], a);
            }
            a += __shfl_down(a, 4, 8);
            a += __shfl_down(a, 2, 8);
            a += __shfl_down(a, 1, 8);
            if (ll == 0) {
                out[((size_t)b * T_ + t) * F_ + fo] = a + blin_f[fo];
            }
        }
        p ^= 1;
    }
}

extern "C" void kernel_launch(void* const* d_in, const int* in_sizes, int n_in,
                              void* d_out, int out_size, void* d_ws, size_t ws_size,
                              hipStream_t stream) {
    const float* x    = (const float*)d_in[0];
    const float* wih0 = (const float*)d_in[1];
    const float* whh0 = (const float*)d_in[2];
    const float* bih0 = (const float*)d_in[3];
    const float* bhh0 = (const float*)d_in[4];
    const float* wih1 = (const float*)d_in[5];
    const float* whh1 = (const float*)d_in[6];
    const float* bih1 = (const float*)d_in[7];
    const float* bhh1 = (const float*)d_in[8];
    const float* wlin = (const float*)d_in[9];
    const float* blin = (const float*)d_in[10];
    float* out = (float*)d_out;

    lstm2_fused_kernel<<<dim3(B_), dim3(512), 0, stream>>>(
        x, wih0, whh0, bih0, bhh0, wih1, whh1, bih1, bhh1, wlin, blin, out);
}